// Round 5
// baseline (270.031 us; speedup 1.0000x reference)
//
#include <hip/hip_runtime.h>
#include <math.h>

#define BB 8
#define NN 1024
#define DIM 768
#define HEADS 12
#define CR 384
#define HD 32
#define MROWS (BB*NN)   // 8192
#define EPS 1e-5f
#define SCALE_Q 0.25503486f   // (1/sqrt(32)) * log2(e): P = exp2(s) directly

typedef __attribute__((ext_vector_type(8))) __bf16 bf16x8;
typedef __attribute__((ext_vector_type(8))) unsigned short u16x8;
typedef __attribute__((ext_vector_type(4))) float f32x4;

__device__ __forceinline__ unsigned short f2bf(float f) {
    unsigned int u = __float_as_uint(f);
    u += 0x7fffu + ((u >> 16) & 1u);   // RNE; finite inputs only
    return (unsigned short)(u >> 16);
}

__device__ __forceinline__ unsigned int packbf2(float lo, float hi) {
    return (unsigned int)f2bf(lo) | ((unsigned int)f2bf(hi) << 16);
}

// async global->LDS, 16B/lane; LDS dest = wave-uniform base + lane*16
__device__ __forceinline__ void async_cp16(const unsigned short* g, unsigned short* l) {
    __builtin_amdgcn_global_load_lds(
        (const __attribute__((address_space(1))) unsigned int*)g,
        (__attribute__((address_space(3))) unsigned int*)l, 16, 0, 0);
}

// ---------------- fused LN -> bf16: block per row ----------------
__global__ __launch_bounds__(256) void ln_bf16(
    const float* __restrict__ A, int K,
    const float* __restrict__ g, const float* __restrict__ bt,
    unsigned short* __restrict__ Y)
{
    const int row = blockIdx.x;
    const int t = threadIdx.x;
    const int nv = K >> 2;
    const float* a = A + (size_t)row * K;
    float4 val = make_float4(0.f, 0.f, 0.f, 0.f);
    float s = 0.f, ss = 0.f;
    if (t < nv) {
        val = ((const float4*)a)[t];
        s = val.x + val.y + val.z + val.w;
        ss = val.x * val.x + val.y * val.y + val.z * val.z + val.w * val.w;
    }
    for (int off = 32; off; off >>= 1) {
        s  += __shfl_down(s, off, 64);
        ss += __shfl_down(ss, off, 64);
    }
    __shared__ float rS[4], rSS[4];
    __shared__ float sh_mu, sh_rs;
    int lane = t & 63, w = t >> 6;
    if (lane == 0) { rS[w] = s; rSS[w] = ss; }
    __syncthreads();
    if (t == 0) {
        float S = rS[0] + rS[1] + rS[2] + rS[3];
        float SS = rSS[0] + rSS[1] + rSS[2] + rSS[3];
        float m = S / K;
        sh_mu = m;
        sh_rs = rsqrtf(SS / K - m * m + EPS);
    }
    __syncthreads();
    if (t < nv) {
        float m = sh_mu, r = sh_rs;
        float4 gv = ((const float4*)g)[t];
        float4 bv = ((const float4*)bt)[t];
        ushort4 o = make_ushort4(
            f2bf((val.x - m) * r * gv.x + bv.x),
            f2bf((val.y - m) * r * gv.y + bv.y),
            f2bf((val.z - m) * r * gv.z + bv.z),
            f2bf((val.w - m) * r * gv.w + bv.w));
        ((ushort4*)(Y + (size_t)row * K))[t] = o;
    }
}

// ---------------- cast weights f32->bf16 ----------------
__global__ __launch_bounds__(256) void cast_weights(
    const float* __restrict__ wp, const float* __restrict__ wq,
    const float* __restrict__ wk, const float* __restrict__ wv,
    unsigned short* __restrict__ wpo, unsigned short* __restrict__ wqkvo)
{
    int i = blockIdx.x * 256 + threadIdx.x;    // float4 index; grid covers 184320
    const float* src; unsigned short* dst; int off;
    if (i < 73728) { src = wp; dst = wpo; off = i; }
    else {
        int j = i - 73728;
        int sel = j / 36864; off = j % 36864;
        src = sel == 0 ? wq : (sel == 1 ? wk : wv);
        dst = wqkvo + (size_t)sel * 147456;
    }
    float4 v = ((const float4*)src)[off];
    ushort4 o = make_ushort4(f2bf(v.x), f2bf(v.y), f2bf(v.z), f2bf(v.w));
    ((ushort4*)dst)[off] = o;
}

// ---------------- bf16 MFMA GEMM, 64x64 tile, double-buffered LDS ----------------
// MODE 0: f32 out (pitch CR) + bias -> C0
// MODE 1: qkv epilogue: cols<384 -> bf16 q (scaled SCALE_Q) into C0 pitch 768;
//         cols 384..767 -> bf16 k into C0; cols>=768 -> V^T bf16 into C1 [ch][token] pitch 8192.
template<int KD, int MODE>
__global__ __launch_bounds__(256) void gemm_mfma(
    const unsigned short* __restrict__ A,    // [M][KD] bf16
    const unsigned short* __restrict__ W,    // [Nout][KD] bf16
    const float* __restrict__ bias,
    void* __restrict__ C0, void* __restrict__ C1)
{
    __shared__ unsigned short Asm[2 * 64 * 32];
    __shared__ unsigned short Bsm[2 * 64 * 32];
    const int t = threadIdx.x;
    const int wave = t >> 6, lane = t & 63;
    const int l15 = lane & 15, quad = lane >> 4;
    const int m0 = blockIdx.y * 64;
    const int n0 = blockIdx.x * 64;
    const int wm = (wave & 1) * 32, wn = (wave >> 1) * 32;

    // staging: lane -> (row = wave*16 + lane/4, k-octet = lane%4); LDS dest = base + lane*16B
    const unsigned short* gA = A + (size_t)(m0 + wave * 16 + (lane >> 2)) * KD + (lane & 3) * 8;
    const unsigned short* gB = W + (size_t)(n0 + wave * 16 + (lane >> 2)) * KD + (lane & 3) * 8;
    unsigned short* lA = Asm + wave * 512;
    unsigned short* lB = Bsm + wave * 512;

    constexpr int NIT = KD / 32;
    async_cp16(gA, lA);
    async_cp16(gB, lB);

    f32x4 acc[2][2];
#pragma unroll
    for (int i = 0; i < 2; i++)
#pragma unroll
        for (int j = 0; j < 2; j++) acc[i][j] = (f32x4){0.f, 0.f, 0.f, 0.f};

    for (int it = 0; it < NIT; it++) {
        __syncthreads();                     // buf[it&1] staged (vmcnt drained at barrier)
        const int cur = it & 1;
        if (it + 1 < NIT) {                  // prefetch next tile into other buffer
            const int nxt = cur ^ 1;
            async_cp16(gA + (it + 1) * 32, lA + nxt * 2048);
            async_cp16(gB + (it + 1) * 32, lB + nxt * 2048);
        }
        const unsigned short* Ab = Asm + cur * 2048;
        const unsigned short* Bb = Bsm + cur * 2048;
        bf16x8 af[2], bfr[2];
#pragma unroll
        for (int i = 0; i < 2; i++)
            af[i] = *(const bf16x8*)(Ab + (wm + i * 16 + l15) * 32 + quad * 8);
#pragma unroll
        for (int j = 0; j < 2; j++)
            bfr[j] = *(const bf16x8*)(Bb + (wn + j * 16 + l15) * 32 + quad * 8);
#pragma unroll
        for (int i = 0; i < 2; i++)
#pragma unroll
            for (int j = 0; j < 2; j++)
                acc[i][j] = __builtin_amdgcn_mfma_f32_16x16x32_bf16(af[i], bfr[j], acc[i][j], 0, 0, 0);
    }

    if constexpr (MODE == 0) {
        float* C = (float*)C0;
        float bv[2];
#pragma unroll
        for (int j = 0; j < 2; j++) bv[j] = bias[n0 + wn + j * 16 + l15];
#pragma unroll
        for (int i = 0; i < 2; i++)
#pragma unroll
            for (int j = 0; j < 2; j++)
#pragma unroll
                for (int reg = 0; reg < 4; reg++) {
                    int row = m0 + wm + i * 16 + quad * 4 + reg;
                    int col = n0 + wn + j * 16 + l15;
                    C[(size_t)row * CR + col] = acc[i][j][reg] + bv[j];
                }
    } else {
        unsigned short* Cqk = (unsigned short*)C0;    // [token][768] bf16: q(scaled)|k
        unsigned short* Vt  = (unsigned short*)C1;    // [ch][8192] bf16
#pragma unroll
        for (int i = 0; i < 2; i++)
#pragma unroll
            for (int j = 0; j < 2; j++) {
                const int colbase = n0 + wn + j * 16;     // uniform per (block, j)
                const int token0 = m0 + wm + i * 16 + quad * 4;
                if (colbase < DIM) {
                    const float sc = (colbase < CR) ? SCALE_Q : 1.f;
#pragma unroll
                    for (int reg = 0; reg < 4; reg++)
                        Cqk[(size_t)(token0 + reg) * DIM + colbase + l15] = f2bf(acc[i][j][reg] * sc);
                } else {
                    const int ch = colbase - DIM + l15;
                    uint2 pk;
                    pk.x = packbf2(acc[i][j][0], acc[i][j][1]);
                    pk.y = packbf2(acc[i][j][2], acc[i][j][3]);
                    *(uint2*)(Vt + (size_t)ch * MROWS + token0) = pk;   // 4 consecutive tokens
                }
            }
    }
}

// ---------------- MFMA flash attention: S^T trick, zero barriers, P-only LDS ----------------
// S^T = mfma(A=K_frag, B=Q_frag): lane holds S^T[key=quad*4+reg][q=l15] -> P key-consecutive
// along reg -> b64 packed writes to wave-private Ps[q][key] (pitch 72).
__global__ __launch_bounds__(256) void attn_mfma(
    const unsigned short* __restrict__ qk,   // [8192][768] bf16: q*SCALE_Q | k
    const unsigned short* __restrict__ vt,   // [384][8192] bf16: V^T
    const float* __restrict__ h, float* __restrict__ out)
{
    const int qt = blockIdx.x;                // 0..15
    const int bh = blockIdx.y;                // 0..95
    const int b = bh / HEADS, head = bh % HEADS;
    const int hc = head * HD;
    const int t = threadIdx.x;
    const int wave = t >> 6, lane = t & 63;
    const int l15 = lane & 15, quad = lane >> 4;
    const int q0 = qt * 64;

    __shared__ unsigned short Ps[4][16 * 72];  // wave-private P [q][key], pitch 72 (16B rows)
    unsigned short* Pw = Ps[wave];

    // Q fragment (B-operand role: B[k=dim][n=q], lane holds Q[q=l15][dim=quad*8+j]); loaded once
    bf16x8 qa = *(const bf16x8*)(qk + (size_t)(b * NN + q0 + wave * 16 + l15) * DIM + hc + quad * 8);

    const unsigned short* Kp = qk + (size_t)(b * NN) * DIM + CR + hc + quad * 8;  // + row*DIM
    const unsigned short* Vp = vt + (size_t)hc * MROWS + b * NN;                  // + ch*MROWS + tok

    f32x4 o[2] = {{0.f,0.f,0.f,0.f},{0.f,0.f,0.f,0.f}};
    float lpart = 0.f;

    for (int kt = 0; kt < 16; kt++) {
        // V B-frags: direct global b128 (contiguous along tokens); issue early to hide latency
        bf16x8 vb[2][2];
#pragma unroll
        for (int kk = 0; kk < 2; kk++)
#pragma unroll
            for (int nt2 = 0; nt2 < 2; nt2++)
                vb[kk][nt2] = *(const bf16x8*)(Vp + (size_t)(nt2 * 16 + l15) * MROWS
                                               + kt * 64 + kk * 32 + quad * 8);
        // K A-frags: direct global b128 (row = key, 64B segments, L1-shared across waves)
        bf16x8 kb[4];
#pragma unroll
        for (int nt = 0; nt < 4; nt++)
            kb[nt] = *(const bf16x8*)(Kp + (size_t)(kt * 64 + nt * 16 + l15) * DIM);

        // S^T tiles: rows=key, cols=q; q pre-scaled so P = exp2(s)
        f32x4 s[4];
#pragma unroll
        for (int nt = 0; nt < 4; nt++) {
            f32x4 z = {0.f, 0.f, 0.f, 0.f};
            s[nt] = __builtin_amdgcn_mfma_f32_16x16x32_bf16(kb[nt], qa, z, 0, 0, 0);
        }

        // exp2, per-lane l partial, pack 4 key-consecutive bf16 -> one b64 LDS write per tile
#pragma unroll
        for (int nt = 0; nt < 4; nt++) {
            float e0 = __builtin_amdgcn_exp2f(s[nt][0]);
            float e1 = __builtin_amdgcn_exp2f(s[nt][1]);
            float e2 = __builtin_amdgcn_exp2f(s[nt][2]);
            float e3 = __builtin_amdgcn_exp2f(s[nt][3]);
            lpart += (e0 + e1) + (e2 + e3);
            uint2 pk;
            pk.x = packbf2(e0, e1);
            pk.y = packbf2(e2, e3);
            *(uint2*)(Pw + l15 * 72 + nt * 16 + quad * 4) = pk;
        }

        // PV: A-frag = P rows (b128, wave-private -> only lgkmcnt wait, no barrier)
#pragma unroll
        for (int kk = 0; kk < 2; kk++) {
            bf16x8 pa = *(const bf16x8*)(Pw + l15 * 72 + kk * 32 + quad * 8);
#pragma unroll
            for (int nt2 = 0; nt2 < 2; nt2++)
                o[nt2] = __builtin_amdgcn_mfma_f32_16x16x32_bf16(pa, vb[kk][nt2], o[nt2], 0, 0, 0);
        }
    }

    // denominator: lane holds partial over its keys for q=l15; combine the 4 quads
    lpart += __shfl_xor(lpart, 16, 64);
    lpart += __shfl_xor(lpart, 32, 64);
    const float linv = 1.f / lpart;            // valid at every lane for q=l15

    // epilogue: out = h + O * linv(q);  O C-layout row=q=quad*4+reg, col=dim=nt2*16+l15
#pragma unroll
    for (int reg = 0; reg < 4; reg++) {
        const float li = __shfl(linv, quad * 4 + reg, 64);
        const size_t row = (size_t)(b * NN + q0 + wave * 16 + quad * 4 + reg);
#pragma unroll
        for (int nt2 = 0; nt2 < 2; nt2++) {
            size_t idx = row * CR + hc + nt2 * 16 + l15;
            out[idx] = h[idx] + o[nt2][reg] * li;
        }
    }
}

extern "C" void kernel_launch(void* const* d_in, const int* in_sizes, int n_in,
                              void* d_out, int out_size, void* d_ws, size_t ws_size,
                              hipStream_t stream) {
    const float* x      = (const float*)d_in[0];
    const float* ln0_g  = (const float*)d_in[1];
    const float* ln0_b  = (const float*)d_in[2];
    const float* w_proj = (const float*)d_in[3];
    const float* b_proj = (const float*)d_in[4];
    const float* ln1_g  = (const float*)d_in[5];
    const float* ln1_b  = (const float*)d_in[6];
    const float* wq     = (const float*)d_in[7];
    const float* wk     = (const float*)d_in[8];
    const float* wv     = (const float*)d_in[9];
    float* out = (float*)d_out;

    // ws layout (39.2 MB): qk aliases a0 (a0 dead after gemm1)
    char* base = (char*)d_ws;
    unsigned short* a0   = (unsigned short*)base;               // 8192*768*2 = 12,582,912
    unsigned short* qkb  = (unsigned short*)base;               // same size, alias
    float*          hbuf = (float*)(base + 12582912);           // 8192*384*4 = 12,582,912
    unsigned short* yb   = (unsigned short*)(base + 25165824);  // 8192*384*2 =  6,291,456
    unsigned short* vtb  = (unsigned short*)(base + 31457280);  // 384*8192*2 =  6,291,456
    unsigned short* wp   = (unsigned short*)(base + 37748736);  // 384*768*2  =    589,824
    unsigned short* wqkv = (unsigned short*)(base + 38338560);  // 1152*384*2 =    884,736

    // 1. a0 = bf16(LN0(x))
    ln_bf16<<<MROWS, 256, 0, stream>>>(x, DIM, ln0_g, ln0_b, a0);
    // 2. weight casts
    cast_weights<<<720, 256, 0, stream>>>(w_proj, wq, wk, wv, wp, wqkv);
    // 3. h = a0 @ wp^T + b_proj  (f32)
    gemm_mfma<DIM, 0><<<dim3(CR / 64, MROWS / 64), 256, 0, stream>>>(
        a0, wp, b_proj, hbuf, nullptr);
    // 4. y = bf16(LN1(h))
    ln_bf16<<<MROWS, 256, 0, stream>>>(hbuf, CR, ln1_g, ln1_b, yb);
    // 5. qk (q scaled) + V^T = y @ wqkv^T
    gemm_mfma<CR, 1><<<dim3(1152 / 64, MROWS / 64), 256, 0, stream>>>(
        yb, wqkv, nullptr, qkb, vtb);
    // 6. out = h + attention
    attn_mfma<<<dim3(NN / 64, BB * HEADS), 256, 0, stream>>>(qkb, vtb, hbuf, out);
}

// Round 6
// 176.092 us; speedup vs baseline: 1.5335x; 1.5335x over previous
//
#include <hip/hip_runtime.h>
#include <math.h>

#define BB 8
#define NN 1024
#define DIM 768
#define HEADS 12
#define CR 384
#define HD 32
#define MROWS (BB*NN)   // 8192
#define EPS 1e-5f
#define SCALE_Q 0.25503486f   // (1/sqrt(32)) * log2(e): P = exp2(s) directly

typedef __attribute__((ext_vector_type(8))) __bf16 bf16x8;
typedef __attribute__((ext_vector_type(8))) unsigned short u16x8;
typedef __attribute__((ext_vector_type(4))) float f32x4;

__device__ __forceinline__ unsigned short f2bf(float f) {
    unsigned int u = __float_as_uint(f);
    u += 0x7fffu + ((u >> 16) & 1u);   // RNE; finite inputs only
    return (unsigned short)(u >> 16);
}

__device__ __forceinline__ unsigned int packbf2(float lo, float hi) {
    return (unsigned int)f2bf(lo) | ((unsigned int)f2bf(hi) << 16);
}

// async global->LDS, 16B/lane; LDS dest = wave-uniform base + lane*16
__device__ __forceinline__ void async_cp16(const unsigned short* g, unsigned short* l) {
    __builtin_amdgcn_global_load_lds(
        (const __attribute__((address_space(1))) unsigned int*)g,
        (__attribute__((address_space(3))) unsigned int*)l, 16, 0, 0);
}

// ---------------- fused LN -> bf16: block per row ----------------
__global__ __launch_bounds__(256) void ln_bf16(
    const float* __restrict__ A, int K,
    const float* __restrict__ g, const float* __restrict__ bt,
    unsigned short* __restrict__ Y)
{
    const int row = blockIdx.x;
    const int t = threadIdx.x;
    const int nv = K >> 2;
    const float* a = A + (size_t)row * K;
    float4 val = make_float4(0.f, 0.f, 0.f, 0.f);
    float s = 0.f, ss = 0.f;
    if (t < nv) {
        val = ((const float4*)a)[t];
        s = val.x + val.y + val.z + val.w;
        ss = val.x * val.x + val.y * val.y + val.z * val.z + val.w * val.w;
    }
    for (int off = 32; off; off >>= 1) {
        s  += __shfl_down(s, off, 64);
        ss += __shfl_down(ss, off, 64);
    }
    __shared__ float rS[4], rSS[4];
    __shared__ float sh_mu, sh_rs;
    int lane = t & 63, w = t >> 6;
    if (lane == 0) { rS[w] = s; rSS[w] = ss; }
    __syncthreads();
    if (t == 0) {
        float S = rS[0] + rS[1] + rS[2] + rS[3];
        float SS = rSS[0] + rSS[1] + rSS[2] + rSS[3];
        float m = S / K;
        sh_mu = m;
        sh_rs = rsqrtf(SS / K - m * m + EPS);
    }
    __syncthreads();
    if (t < nv) {
        float m = sh_mu, r = sh_rs;
        float4 gv = ((const float4*)g)[t];
        float4 bv = ((const float4*)bt)[t];
        ushort4 o = make_ushort4(
            f2bf((val.x - m) * r * gv.x + bv.x),
            f2bf((val.y - m) * r * gv.y + bv.y),
            f2bf((val.z - m) * r * gv.z + bv.z),
            f2bf((val.w - m) * r * gv.w + bv.w));
        ((ushort4*)(Y + (size_t)row * K))[t] = o;
    }
}

// ---------------- cast weights f32->bf16 ----------------
__global__ __launch_bounds__(256) void cast_weights(
    const float* __restrict__ wp, const float* __restrict__ wq,
    const float* __restrict__ wk, const float* __restrict__ wv,
    unsigned short* __restrict__ wpo, unsigned short* __restrict__ wqkvo)
{
    int i = blockIdx.x * 256 + threadIdx.x;    // float4 index; grid covers 184320
    const float* src; unsigned short* dst; int off;
    if (i < 73728) { src = wp; dst = wpo; off = i; }
    else {
        int j = i - 73728;
        int sel = j / 36864; off = j % 36864;
        src = sel == 0 ? wq : (sel == 1 ? wk : wv);
        dst = wqkvo + (size_t)sel * 147456;
    }
    float4 v = ((const float4*)src)[off];
    ushort4 o = make_ushort4(f2bf(v.x), f2bf(v.y), f2bf(v.z), f2bf(v.w));
    ((ushort4*)dst)[off] = o;
}

// ---------------- bf16 MFMA GEMM, 128x128 tile (m97 pattern), dbuf LDS + prefetch ----------------
// MODE 0: f32 out (pitch CR) + bias -> C0
// MODE 1: qkv epilogue: cols<384 -> bf16 q*SCALE_Q into C0 pitch 768; 384..767 -> bf16 k into C0;
//         cols>=768 -> V^T bf16 into C1 [ch][token] pitch 8192.
template<int KD, int MODE>
__global__ __launch_bounds__(256) void gemm_mfma(
    const unsigned short* __restrict__ A,    // [M][KD] bf16
    const unsigned short* __restrict__ W,    // [Nout][KD] bf16
    const float* __restrict__ bias,
    void* __restrict__ C0, void* __restrict__ C1)
{
    __shared__ unsigned short Asm[2 * 128 * 32];   // 16 KB
    __shared__ unsigned short Bsm[2 * 128 * 32];
    const int t = threadIdx.x;
    const int wave = t >> 6, lane = t & 63;
    const int l15 = lane & 15, quad = lane >> 4;
    const int m0 = blockIdx.y * 128;
    const int n0 = blockIdx.x * 128;
    const int wm = (wave & 1) * 64, wn = (wave >> 1) * 64;

    // staging: lane -> (row = wave*32 + lane/4 [+16 on 2nd issue], k-octet = lane%4)
    const int srow = lane >> 2;
    const int skq  = (lane & 3) * 8;
    const unsigned short* gA = A + (size_t)(m0 + wave * 32 + srow) * KD + skq;
    const unsigned short* gB = W + (size_t)(n0 + wave * 32 + srow) * KD + skq;
    unsigned short* lA = Asm + wave * 1024;   // 32 rows * 32 elems per wave
    unsigned short* lB = Bsm + wave * 1024;

    constexpr int NIT = KD / 32;
    // stage it=0 into buffer 0
    async_cp16(gA, lA);
    async_cp16(gA + (size_t)16 * KD, lA + 512);
    async_cp16(gB, lB);
    async_cp16(gB + (size_t)16 * KD, lB + 512);

    f32x4 acc[4][4];
#pragma unroll
    for (int i = 0; i < 4; i++)
#pragma unroll
        for (int j = 0; j < 4; j++) acc[i][j] = (f32x4){0.f, 0.f, 0.f, 0.f};

    for (int it = 0; it < NIT; it++) {
        __syncthreads();                     // buf[it&1] staged (vmcnt drained at barrier)
        const int cur = it & 1;
        if (it + 1 < NIT) {                  // prefetch next k-tile into other buffer
            const int noff = (cur ^ 1) * 4096;
            async_cp16(gA + (it + 1) * 32, lA + noff);
            async_cp16(gA + (size_t)16 * KD + (it + 1) * 32, lA + noff + 512);
            async_cp16(gB + (it + 1) * 32, lB + noff);
            async_cp16(gB + (size_t)16 * KD + (it + 1) * 32, lB + noff + 512);
        }
        const unsigned short* Ab = Asm + cur * 4096;
        const unsigned short* Bb = Bsm + cur * 4096;
        bf16x8 af[4], bfr[4];
#pragma unroll
        for (int i = 0; i < 4; i++)
            af[i] = *(const bf16x8*)(Ab + (wm + i * 16 + l15) * 32 + quad * 8);
#pragma unroll
        for (int j = 0; j < 4; j++)
            bfr[j] = *(const bf16x8*)(Bb + (wn + j * 16 + l15) * 32 + quad * 8);
#pragma unroll
        for (int i = 0; i < 4; i++)
#pragma unroll
            for (int j = 0; j < 4; j++)
                acc[i][j] = __builtin_amdgcn_mfma_f32_16x16x32_bf16(af[i], bfr[j], acc[i][j], 0, 0, 0);
    }

    if constexpr (MODE == 0) {
        float* C = (float*)C0;
        float bv[4];
#pragma unroll
        for (int j = 0; j < 4; j++) bv[j] = bias[n0 + wn + j * 16 + l15];
#pragma unroll
        for (int i = 0; i < 4; i++)
#pragma unroll
            for (int j = 0; j < 4; j++)
#pragma unroll
                for (int reg = 0; reg < 4; reg++) {
                    int row = m0 + wm + i * 16 + quad * 4 + reg;
                    int col = n0 + wn + j * 16 + l15;
                    C[(size_t)row * CR + col] = acc[i][j][reg] + bv[j];
                }
    } else {
        unsigned short* Cqk = (unsigned short*)C0;    // [token][768] bf16: q(scaled)|k
        unsigned short* Vt  = (unsigned short*)C1;    // [ch][8192] bf16
#pragma unroll
        for (int i = 0; i < 4; i++)
#pragma unroll
            for (int j = 0; j < 4; j++) {
                const int colbase = n0 + wn + j * 16;     // uniform per (block, j)
                const int token0 = m0 + wm + i * 16 + quad * 4;
                if (colbase < DIM) {
                    const float sc = (colbase < CR) ? SCALE_Q : 1.f;
#pragma unroll
                    for (int reg = 0; reg < 4; reg++)
                        Cqk[(size_t)(token0 + reg) * DIM + colbase + l15] = f2bf(acc[i][j][reg] * sc);
                } else {
                    const int ch = colbase - DIM + l15;
                    uint2 pk;
                    pk.x = packbf2(acc[i][j][0], acc[i][j][1]);
                    pk.y = packbf2(acc[i][j][2], acc[i][j][3]);
                    *(uint2*)(Vt + (size_t)ch * MROWS + token0) = pk;   // 4 consecutive tokens
                }
            }
    }
}

// ---------------- MFMA flash attention: coop LDS staging + reg prefetch + S^T compute core ----------------
// S^T = mfma(A=K_frag, B=Q_frag): lane holds S^T[key=quad*4+reg][q=l15] -> packed b64 P writes.
// K staged [key][32] pitch 40; V^T staged [ch][64 keys] pitch 72 (straight copy from global V^T).
__global__ __launch_bounds__(256) void attn_mfma(
    const unsigned short* __restrict__ qk,   // [8192][768] bf16: q*SCALE_Q | k
    const unsigned short* __restrict__ vt,   // [384][8192] bf16: V^T
    const float* __restrict__ h, float* __restrict__ out)
{
    const int qt = blockIdx.x;                // 0..15
    const int bh = blockIdx.y;                // 0..95
    const int b = bh / HEADS, head = bh % HEADS;
    const int hc = head * HD;
    const int t = threadIdx.x;
    const int wave = t >> 6, lane = t & 63;
    const int l15 = lane & 15, quad = lane >> 4;
    const int q0 = qt * 64;

    __shared__ unsigned short Ks[64 * 40];     // [key][dim] pitch 40
    __shared__ unsigned short Vs[32 * 72];     // [ch][key] pitch 72
    __shared__ unsigned short Ps[4][16 * 72];  // wave-private P [q][key] pitch 72
    unsigned short* Pw = Ps[wave];

    // Q fragment (B-operand: lane holds Q[q=l15][dim=quad*8+j]); loaded once, pre-scaled in GEMM
    bf16x8 qa = *(const bf16x8*)(qk + (size_t)(b * NN + q0 + wave * 16 + l15) * DIM + hc + quad * 8);

    // staging maps (coalesced): K: 4 lanes per key row (64B); V: 8 lanes per ch row (128B)
    const int rr = t >> 2, seg = t & 3;
    const unsigned short* gK = qk + (size_t)(b * NN + rr) * DIM + CR + hc + seg * 8;
    const int vch = wave * 8 + (lane >> 3), vko = (lane & 7) * 8;
    const unsigned short* gV = vt + (size_t)(hc + vch) * MROWS + b * NN + vko;

    u16x8 kreg = *(const u16x8*)gK;            // kt = 0
    u16x8 vreg = *(const u16x8*)gV;

    f32x4 o[2] = {{0.f,0.f,0.f,0.f},{0.f,0.f,0.f,0.f}};
    float lpart = 0.f;

    for (int kt = 0; kt < 16; kt++) {
        __syncthreads();                       // prev tile's LDS reads done
        *(u16x8*)(Ks + rr * 40 + seg * 8) = kreg;
        *(u16x8*)(Vs + vch * 72 + vko) = vreg;
        if (kt < 15) {                         // reg prefetch: plain VGPR loads don't drain at barrier
            kreg = *(const u16x8*)(gK + (size_t)(kt + 1) * 64 * DIM);
            vreg = *(const u16x8*)(gV + (kt + 1) * 64);
        }
        __syncthreads();                       // staging visible

        // S^T tiles: rows=key, cols=q (4 MFMAs, K=32)
        f32x4 s[4];
#pragma unroll
        for (int nt = 0; nt < 4; nt++) {
            bf16x8 kb = *(const bf16x8*)(Ks + (nt * 16 + l15) * 40 + quad * 8);
            f32x4 z = {0.f, 0.f, 0.f, 0.f};
            s[nt] = __builtin_amdgcn_mfma_f32_16x16x32_bf16(kb, qa, z, 0, 0, 0);
        }

        // P = exp2(s); per-lane l partial; 4 key-consecutive bf16 -> one b64 LDS write per tile
#pragma unroll
        for (int nt = 0; nt < 4; nt++) {
            float e0 = __builtin_amdgcn_exp2f(s[nt][0]);
            float e1 = __builtin_amdgcn_exp2f(s[nt][1]);
            float e2 = __builtin_amdgcn_exp2f(s[nt][2]);
            float e3 = __builtin_amdgcn_exp2f(s[nt][3]);
            lpart += (e0 + e1) + (e2 + e3);
            uint2 pk;
            pk.x = packbf2(e0, e1);
            pk.y = packbf2(e2, e3);
            *(uint2*)(Pw + l15 * 72 + nt * 16 + quad * 4) = pk;
        }

        // PV: A-frag = P rows (wave-private, lgkmcnt only); B-frag = V^T tile b128
#pragma unroll
        for (int kk = 0; kk < 2; kk++) {
            bf16x8 pa = *(const bf16x8*)(Pw + l15 * 72 + kk * 32 + quad * 8);
#pragma unroll
            for (int nt2 = 0; nt2 < 2; nt2++) {
                bf16x8 vb = *(const bf16x8*)(Vs + (nt2 * 16 + l15) * 72 + kk * 32 + quad * 8);
                o[nt2] = __builtin_amdgcn_mfma_f32_16x16x32_bf16(pa, vb, o[nt2], 0, 0, 0);
            }
        }
    }

    // denominator: lane holds partial over its keys for q=l15; combine the 4 quads
    lpart += __shfl_xor(lpart, 16, 64);
    lpart += __shfl_xor(lpart, 32, 64);
    const float linv = 1.f / lpart;

    // epilogue: out = h + O * linv(q);  O C-layout row=q=quad*4+reg, col=dim=nt2*16+l15
#pragma unroll
    for (int reg = 0; reg < 4; reg++) {
        const float li = __shfl(linv, quad * 4 + reg, 64);
        const size_t row = (size_t)(b * NN + q0 + wave * 16 + quad * 4 + reg);
#pragma unroll
        for (int nt2 = 0; nt2 < 2; nt2++) {
            size_t idx = row * CR + hc + nt2 * 16 + l15;
            out[idx] = h[idx] + o[nt2][reg] * li;
        }
    }
}

extern "C" void kernel_launch(void* const* d_in, const int* in_sizes, int n_in,
                              void* d_out, int out_size, void* d_ws, size_t ws_size,
                              hipStream_t stream) {
    const float* x      = (const float*)d_in[0];
    const float* ln0_g  = (const float*)d_in[1];
    const float* ln0_b  = (const float*)d_in[2];
    const float* w_proj = (const float*)d_in[3];
    const float* b_proj = (const float*)d_in[4];
    const float* ln1_g  = (const float*)d_in[5];
    const float* ln1_b  = (const float*)d_in[6];
    const float* wq     = (const float*)d_in[7];
    const float* wk     = (const float*)d_in[8];
    const float* wv     = (const float*)d_in[9];
    float* out = (float*)d_out;

    // ws layout (39.2 MB): qk aliases a0 (a0 dead after gemm1)
    char* base = (char*)d_ws;
    unsigned short* a0   = (unsigned short*)base;               // 8192*768*2 = 12,582,912
    unsigned short* qkb  = (unsigned short*)base;               // same size, alias
    float*          hbuf = (float*)(base + 12582912);           // 8192*384*4 = 12,582,912
    unsigned short* yb   = (unsigned short*)(base + 25165824);  // 8192*384*2 =  6,291,456
    unsigned short* vtb  = (unsigned short*)(base + 31457280);  // 384*8192*2 =  6,291,456
    unsigned short* wp   = (unsigned short*)(base + 37748736);  // 384*768*2  =    589,824
    unsigned short* wqkv = (unsigned short*)(base + 38338560);  // 1152*384*2 =    884,736

    // 1. a0 = bf16(LN0(x))
    ln_bf16<<<MROWS, 256, 0, stream>>>(x, DIM, ln0_g, ln0_b, a0);
    // 2. weight casts
    cast_weights<<<720, 256, 0, stream>>>(w_proj, wq, wk, wv, wp, wqkv);
    // 3. h = a0 @ wp^T + b_proj  (f32, 128x128 MFMA)
    gemm_mfma<DIM, 0><<<dim3(CR / 128, MROWS / 128), 256, 0, stream>>>(
        a0, wp, b_proj, hbuf, nullptr);
    // 4. y = bf16(LN1(h))
    ln_bf16<<<MROWS, 256, 0, stream>>>(hbuf, CR, ln1_g, ln1_b, yb);
    // 5. qk (q scaled) + V^T = y @ wqkv^T  (128x128 MFMA)
    gemm_mfma<CR, 1><<<dim3(1152 / 128, MROWS / 128), 256, 0, stream>>>(
        yb, wqkv, nullptr, qkb, vtb);
    // 6. out = h + attention
    attn_mfma<<<dim3(NN / 64, BB * HEADS), 256, 0, stream>>>(qkb, vtb, hbuf, out);
}

// Round 7
// 165.271 us; speedup vs baseline: 1.6339x; 1.0655x over previous
//
#include <hip/hip_runtime.h>
#include <math.h>

#define BB 8
#define NN 1024
#define DIM 768
#define HEADS 12
#define CR 384
#define HD 32
#define MROWS (BB*NN)   // 8192
#define EPS 1e-5f
#define SCALE_Q 0.25503486f   // (1/sqrt(32)) * log2(e): P = exp2(s) directly

typedef __attribute__((ext_vector_type(8))) __bf16 bf16x8;
typedef __attribute__((ext_vector_type(8))) unsigned short u16x8;
typedef __attribute__((ext_vector_type(4))) float f32x4;

__device__ __forceinline__ unsigned short f2bf(float f) {
    unsigned int u = __float_as_uint(f);
    u += 0x7fffu + ((u >> 16) & 1u);   // RNE; finite inputs only
    return (unsigned short)(u >> 16);
}

__device__ __forceinline__ unsigned int packbf2(float lo, float hi) {
    return (unsigned int)f2bf(lo) | ((unsigned int)f2bf(hi) << 16);
}

// async global->LDS, 16B/lane; LDS dest = wave-uniform base + lane*16
__device__ __forceinline__ void async_cp16(const unsigned short* g, unsigned short* l) {
    __builtin_amdgcn_global_load_lds(
        (const __attribute__((address_space(1))) unsigned int*)g,
        (__attribute__((address_space(3))) unsigned int*)l, 16, 0, 0);
}

// ---------------- fused LN0 -> bf16  +  weight casts (partitioned grid) ----------------
// blocks [0,8192): LN row of x -> a0.  blocks [8192, 8192+720): f32->bf16 weight cast chunks.
__global__ __launch_bounds__(256) void ln0_cast(
    const float* __restrict__ x,
    const float* __restrict__ g, const float* __restrict__ bt,
    unsigned short* __restrict__ a0,
    const float* __restrict__ wp, const float* __restrict__ wq,
    const float* __restrict__ wk, const float* __restrict__ wv,
    unsigned short* __restrict__ wpo, unsigned short* __restrict__ wqkvo)
{
    const int bx = blockIdx.x;
    const int t = threadIdx.x;
    if (bx >= MROWS) {   // weight-cast partition
        int i = (bx - MROWS) * 256 + t;       // float4 index, covers 184320
        const float* src; unsigned short* dst; int off;
        if (i < 73728) { src = wp; dst = wpo; off = i; }
        else {
            int j = i - 73728;
            int sel = j / 36864; off = j % 36864;
            src = sel == 0 ? wq : (sel == 1 ? wk : wv);
            dst = wqkvo + (size_t)sel * 147456;
        }
        float4 v = ((const float4*)src)[off];
        ((ushort4*)dst)[off] = make_ushort4(f2bf(v.x), f2bf(v.y), f2bf(v.z), f2bf(v.w));
        return;
    }
    // LN0 partition: one row of x[8192][768]
    const int nv = DIM >> 2;                  // 192 float4
    const float* a = x + (size_t)bx * DIM;
    float4 val = make_float4(0.f, 0.f, 0.f, 0.f);
    float s = 0.f, ss = 0.f;
    if (t < nv) {
        val = ((const float4*)a)[t];
        s = val.x + val.y + val.z + val.w;
        ss = val.x * val.x + val.y * val.y + val.z * val.z + val.w * val.w;
    }
    for (int off = 32; off; off >>= 1) {
        s  += __shfl_down(s, off, 64);
        ss += __shfl_down(ss, off, 64);
    }
    __shared__ float rS[4], rSS[4];
    __shared__ float sh_mu, sh_rs;
    int lane = t & 63, w = t >> 6;
    if (lane == 0) { rS[w] = s; rSS[w] = ss; }
    __syncthreads();
    if (t == 0) {
        float S = rS[0] + rS[1] + rS[2] + rS[3];
        float SS = rSS[0] + rSS[1] + rSS[2] + rSS[3];
        float m = S / DIM;
        sh_mu = m;
        sh_rs = rsqrtf(SS / DIM - m * m + EPS);
    }
    __syncthreads();
    if (t < nv) {
        float m = sh_mu, r = sh_rs;
        float4 gv = ((const float4*)g)[t];
        float4 bv = ((const float4*)bt)[t];
        ((ushort4*)(a0 + (size_t)bx * DIM))[t] = make_ushort4(
            f2bf((val.x - m) * r * gv.x + bv.x),
            f2bf((val.y - m) * r * gv.y + bv.y),
            f2bf((val.z - m) * r * gv.z + bv.z),
            f2bf((val.w - m) * r * gv.w + bv.w));
    }
}

// ---------------- ln1_sum: hs = h0+h1+bias; y = bf16(LN1(hs)); write hs (f32) + y ----------------
__global__ __launch_bounds__(128) void ln1_sum(
    const float* __restrict__ h0, const float* __restrict__ h1,
    const float* __restrict__ bias,
    const float* __restrict__ g, const float* __restrict__ bt,
    float* __restrict__ hs, unsigned short* __restrict__ y)
{
    const int row = blockIdx.x;
    const int t = threadIdx.x;
    const int nv = CR >> 2;                   // 96 float4
    float4 val = make_float4(0.f, 0.f, 0.f, 0.f);
    float s = 0.f, ss = 0.f;
    if (t < nv) {
        float4 v0 = ((const float4*)(h0 + (size_t)row * CR))[t];
        float4 v1 = ((const float4*)(h1 + (size_t)row * CR))[t];
        float4 bv = ((const float4*)bias)[t];
        val = make_float4(v0.x + v1.x + bv.x, v0.y + v1.y + bv.y,
                          v0.z + v1.z + bv.z, v0.w + v1.w + bv.w);
        ((float4*)(hs + (size_t)row * CR))[t] = val;
        s = val.x + val.y + val.z + val.w;
        ss = val.x * val.x + val.y * val.y + val.z * val.z + val.w * val.w;
    }
    for (int off = 32; off; off >>= 1) {
        s  += __shfl_down(s, off, 64);
        ss += __shfl_down(ss, off, 64);
    }
    __shared__ float rS[2], rSS[2];
    __shared__ float sh_mu, sh_rs;
    int lane = t & 63, w = t >> 6;
    if (lane == 0) { rS[w] = s; rSS[w] = ss; }
    __syncthreads();
    if (t == 0) {
        float S = rS[0] + rS[1];
        float SS = rSS[0] + rSS[1];
        float m = S / CR;
        sh_mu = m;
        sh_rs = rsqrtf(SS / CR - m * m + EPS);
    }
    __syncthreads();
    if (t < nv) {
        float m = sh_mu, r = sh_rs;
        float4 gv = ((const float4*)g)[t];
        float4 bv = ((const float4*)bt)[t];
        ((ushort4*)(y + (size_t)row * CR))[t] = make_ushort4(
            f2bf((val.x - m) * r * gv.x + bv.x),
            f2bf((val.y - m) * r * gv.y + bv.y),
            f2bf((val.z - m) * r * gv.z + bv.z),
            f2bf((val.w - m) * r * gv.w + bv.w));
    }
}

// ---------------- bf16 MFMA GEMM, 128x128 tile, dbuf LDS + prefetch, optional split-K ----------------
// MODE 0: f32 partial out (pitch CR, no bias) -> C0 + blockIdx.z*MROWS*CR
// MODE 1: qkv epilogue: cols<384 -> bf16 q*SCALE_Q into C0 pitch 768; 384..767 -> bf16 k into C0;
//         cols>=768 -> V^T bf16 into C1 [ch][token] pitch 8192.
template<int KD, int NITER, int MODE>
__global__ __launch_bounds__(256) void gemm_mfma(
    const unsigned short* __restrict__ A,    // [M][KD] bf16
    const unsigned short* __restrict__ W,    // [Nout][KD] bf16
    void* __restrict__ C0, void* __restrict__ C1)
{
    __shared__ unsigned short Asm[2 * 128 * 32];   // 16 KB
    __shared__ unsigned short Bsm[2 * 128 * 32];
    const int t = threadIdx.x;
    const int wave = t >> 6, lane = t & 63;
    const int l15 = lane & 15, quad = lane >> 4;
    const int m0 = blockIdx.y * 128;
    const int n0 = blockIdx.x * 128;
    const int koff = blockIdx.z * (NITER * 32);
    const int wm = (wave & 1) * 64, wn = (wave >> 1) * 64;

    const int srow = lane >> 2;
    const int skq  = (lane & 3) * 8;
    const unsigned short* gA = A + (size_t)(m0 + wave * 32 + srow) * KD + koff + skq;
    const unsigned short* gB = W + (size_t)(n0 + wave * 32 + srow) * KD + koff + skq;
    unsigned short* lA = Asm + wave * 1024;
    unsigned short* lB = Bsm + wave * 1024;

    async_cp16(gA, lA);
    async_cp16(gA + (size_t)16 * KD, lA + 512);
    async_cp16(gB, lB);
    async_cp16(gB + (size_t)16 * KD, lB + 512);

    f32x4 acc[4][4];
#pragma unroll
    for (int i = 0; i < 4; i++)
#pragma unroll
        for (int j = 0; j < 4; j++) acc[i][j] = (f32x4){0.f, 0.f, 0.f, 0.f};

    for (int it = 0; it < NITER; it++) {
        __syncthreads();                     // buf[it&1] staged (vmcnt drained at barrier)
        const int cur = it & 1;
        if (it + 1 < NITER) {
            const int noff = (cur ^ 1) * 4096;
            async_cp16(gA + (it + 1) * 32, lA + noff);
            async_cp16(gA + (size_t)16 * KD + (it + 1) * 32, lA + noff + 512);
            async_cp16(gB + (it + 1) * 32, lB + noff);
            async_cp16(gB + (size_t)16 * KD + (it + 1) * 32, lB + noff + 512);
        }
        const unsigned short* Ab = Asm + cur * 4096;
        const unsigned short* Bb = Bsm + cur * 4096;
        bf16x8 af[4], bfr[4];
#pragma unroll
        for (int i = 0; i < 4; i++)
            af[i] = *(const bf16x8*)(Ab + (wm + i * 16 + l15) * 32 + quad * 8);
#pragma unroll
        for (int j = 0; j < 4; j++)
            bfr[j] = *(const bf16x8*)(Bb + (wn + j * 16 + l15) * 32 + quad * 8);
#pragma unroll
        for (int i = 0; i < 4; i++)
#pragma unroll
            for (int j = 0; j < 4; j++)
                acc[i][j] = __builtin_amdgcn_mfma_f32_16x16x32_bf16(af[i], bfr[j], acc[i][j], 0, 0, 0);
    }

    if constexpr (MODE == 0) {
        float* C = (float*)C0 + (size_t)blockIdx.z * MROWS * CR;
#pragma unroll
        for (int i = 0; i < 4; i++)
#pragma unroll
            for (int j = 0; j < 4; j++)
#pragma unroll
                for (int reg = 0; reg < 4; reg++) {
                    int row = m0 + wm + i * 16 + quad * 4 + reg;
                    int col = n0 + wn + j * 16 + l15;
                    C[(size_t)row * CR + col] = acc[i][j][reg];
                }
    } else {
        unsigned short* Cqk = (unsigned short*)C0;    // [token][768] bf16: q(scaled)|k
        unsigned short* Vt  = (unsigned short*)C1;    // [ch][8192] bf16
#pragma unroll
        for (int i = 0; i < 4; i++)
#pragma unroll
            for (int j = 0; j < 4; j++) {
                const int colbase = n0 + wn + j * 16;     // uniform per (block, j)
                const int token0 = m0 + wm + i * 16 + quad * 4;
                if (colbase < DIM) {
                    const float sc = (colbase < CR) ? SCALE_Q : 1.f;
#pragma unroll
                    for (int reg = 0; reg < 4; reg++)
                        Cqk[(size_t)(token0 + reg) * DIM + colbase + l15] = f2bf(acc[i][j][reg] * sc);
                } else {
                    const int ch = colbase - DIM + l15;
                    uint2 pk;
                    pk.x = packbf2(acc[i][j][0], acc[i][j][1]);
                    pk.y = packbf2(acc[i][j][2], acc[i][j][3]);
                    *(uint2*)(Vt + (size_t)ch * MROWS + token0) = pk;   // 4 consecutive tokens
                }
            }
    }
}

// ---------------- MFMA flash attention: 128-q blocks, S^T core, coop staging + reg prefetch ----------------
// wave owns 32 q-rows (2 Q B-frags); staged K/V tile feeds 16 MFMAs per kt.
__global__ __launch_bounds__(256) void attn_mfma(
    const unsigned short* __restrict__ qk,   // [8192][768] bf16: q*SCALE_Q | k
    const unsigned short* __restrict__ vt,   // [384][8192] bf16: V^T
    const float* __restrict__ h, float* __restrict__ out)
{
    const int qt = blockIdx.x;                // 0..7 (128-q tiles)
    const int bh = blockIdx.y;                // 0..95
    const int b = bh / HEADS, head = bh % HEADS;
    const int hc = head * HD;
    const int t = threadIdx.x;
    const int wave = t >> 6, lane = t & 63;
    const int l15 = lane & 15, quad = lane >> 4;
    const int q0 = qt * 128;

    __shared__ unsigned short Ks[64 * 40];     // [key][dim] pitch 40
    __shared__ unsigned short Vs[32 * 72];     // [ch][key] pitch 72
    __shared__ unsigned short Ps[4][32 * 72];  // wave-private P [q(32)][key] pitch 72
    unsigned short* Pw = Ps[wave];

    // 2 Q B-frags (rows wave*32 + qi*16 + l15), pre-scaled by SCALE_Q in GEMM epilogue
    bf16x8 qa[2];
#pragma unroll
    for (int qi = 0; qi < 2; qi++)
        qa[qi] = *(const bf16x8*)(qk + (size_t)(b * NN + q0 + wave * 32 + qi * 16 + l15) * DIM
                                  + hc + quad * 8);

    // staging maps (coalesced): K: 4 lanes per key row; V: 8 lanes per ch row
    const int rr = t >> 2, seg = t & 3;
    const unsigned short* gK = qk + (size_t)(b * NN + rr) * DIM + CR + hc + seg * 8;
    const int vch = wave * 8 + (lane >> 3), vko = (lane & 7) * 8;
    const unsigned short* gV = vt + (size_t)(hc + vch) * MROWS + b * NN + vko;

    u16x8 kreg = *(const u16x8*)gK;            // kt = 0
    u16x8 vreg = *(const u16x8*)gV;

    f32x4 o[2][2] = {{{0.f,0.f,0.f,0.f},{0.f,0.f,0.f,0.f}},
                     {{0.f,0.f,0.f,0.f},{0.f,0.f,0.f,0.f}}};
    float lpart[2] = {0.f, 0.f};

    for (int kt = 0; kt < 16; kt++) {
        __syncthreads();                       // prev tile's LDS reads done
        *(u16x8*)(Ks + rr * 40 + seg * 8) = kreg;
        *(u16x8*)(Vs + vch * 72 + vko) = vreg;
        if (kt < 15) {                         // reg prefetch (plain loads don't drain at barrier)
            kreg = *(const u16x8*)(gK + (size_t)(kt + 1) * 64 * DIM);
            vreg = *(const u16x8*)(gV + (kt + 1) * 64);
        }
        __syncthreads();                       // staging visible

        // K A-frags shared across both q-subtiles
        bf16x8 kb[4];
#pragma unroll
        for (int nt = 0; nt < 4; nt++)
            kb[nt] = *(const bf16x8*)(Ks + (nt * 16 + l15) * 40 + quad * 8);

#pragma unroll
        for (int qi = 0; qi < 2; qi++) {
            // S^T tiles: rows=key, cols=q
            f32x4 s[4];
#pragma unroll
            for (int nt = 0; nt < 4; nt++) {
                f32x4 z = {0.f, 0.f, 0.f, 0.f};
                s[nt] = __builtin_amdgcn_mfma_f32_16x16x32_bf16(kb[nt], qa[qi], z, 0, 0, 0);
            }
            // P = exp2(s); per-lane l partial; packed b64 writes (key-consecutive along reg)
#pragma unroll
            for (int nt = 0; nt < 4; nt++) {
                float e0 = __builtin_amdgcn_exp2f(s[nt][0]);
                float e1 = __builtin_amdgcn_exp2f(s[nt][1]);
                float e2 = __builtin_amdgcn_exp2f(s[nt][2]);
                float e3 = __builtin_amdgcn_exp2f(s[nt][3]);
                lpart[qi] += (e0 + e1) + (e2 + e3);
                uint2 pk;
                pk.x = packbf2(e0, e1);
                pk.y = packbf2(e2, e3);
                *(uint2*)(Pw + (qi * 16 + l15) * 72 + nt * 16 + quad * 4) = pk;
            }
        }

        // V B-frags shared across q-subtiles
        bf16x8 vb[2][2];
#pragma unroll
        for (int kk = 0; kk < 2; kk++)
#pragma unroll
            for (int nt2 = 0; nt2 < 2; nt2++)
                vb[kk][nt2] = *(const bf16x8*)(Vs + (nt2 * 16 + l15) * 72 + kk * 32 + quad * 8);

        // PV
#pragma unroll
        for (int qi = 0; qi < 2; qi++)
#pragma unroll
            for (int kk = 0; kk < 2; kk++) {
                bf16x8 pa = *(const bf16x8*)(Pw + (qi * 16 + l15) * 72 + kk * 32 + quad * 8);
#pragma unroll
                for (int nt2 = 0; nt2 < 2; nt2++)
                    o[qi][nt2] = __builtin_amdgcn_mfma_f32_16x16x32_bf16(pa, vb[kk][nt2], o[qi][nt2], 0, 0, 0);
            }
    }

    // epilogue per q-subtile
#pragma unroll
    for (int qi = 0; qi < 2; qi++) {
        float l = lpart[qi];
        l += __shfl_xor(l, 16, 64);
        l += __shfl_xor(l, 32, 64);
        const float linv = 1.f / l;            // denominator for q=l15
#pragma unroll
        for (int reg = 0; reg < 4; reg++) {
            const float li = __shfl(linv, quad * 4 + reg, 64);
            const size_t row = (size_t)(b * NN + q0 + wave * 32 + qi * 16 + quad * 4 + reg);
#pragma unroll
            for (int nt2 = 0; nt2 < 2; nt2++) {
                size_t idx = row * CR + hc + nt2 * 16 + l15;
                out[idx] = h[idx] + o[qi][nt2][reg] * li;
            }
        }
    }
}

extern "C" void kernel_launch(void* const* d_in, const int* in_sizes, int n_in,
                              void* d_out, int out_size, void* d_ws, size_t ws_size,
                              hipStream_t stream) {
    const float* x      = (const float*)d_in[0];
    const float* ln0_g  = (const float*)d_in[1];
    const float* ln0_b  = (const float*)d_in[2];
    const float* w_proj = (const float*)d_in[3];
    const float* b_proj = (const float*)d_in[4];
    const float* ln1_g  = (const float*)d_in[5];
    const float* ln1_b  = (const float*)d_in[6];
    const float* wq     = (const float*)d_in[7];
    const float* wk     = (const float*)d_in[8];
    const float* wv     = (const float*)d_in[9];
    float* out = (float*)d_out;

    // ws layout (64.4 MB): qkb aliases a0 (a0 dead after gemm1 reads it)
    char* base = (char*)d_ws;
    unsigned short* a0   = (unsigned short*)base;               // 8192*768*2 = 12,582,912
    unsigned short* qkb  = (unsigned short*)base;               // alias
    float*          hp   = (float*)(base + 12582912);           // 2 x 8192*384*4 = 25,165,824 (split-K partials)
    float*          hbuf = (float*)(base + 37748736);           // 8192*384*4 = 12,582,912 (hsum)
    unsigned short* yb   = (unsigned short*)(base + 50331648);  // 8192*384*2 =  6,291,456
    unsigned short* vtb  = (unsigned short*)(base + 56623104);  // 384*8192*2 =  6,291,456
    unsigned short* wp   = (unsigned short*)(base + 62914560);  // 384*768*2  =    589,824
    unsigned short* wqkv = (unsigned short*)(base + 63504384);  // 1152*384*2 =    884,736

    // 1. a0 = bf16(LN0(x)) + weight casts (fused, partitioned grid)
    ln0_cast<<<MROWS + 720, 256, 0, stream>>>(x, ln0_g, ln0_b, a0,
                                              w_proj, wq, wk, wv, wp, wqkv);
    // 2. split-K gemm1: hp[z] = a0 @ wp^T (K-half z)
    gemm_mfma<DIM, 12, 0><<<dim3(CR / 128, MROWS / 128, 2), 256, 0, stream>>>(
        a0, wp, hp, nullptr);
    // 3. hsum = hp0+hp1+b_proj; y = bf16(LN1(hsum))
    ln1_sum<<<MROWS, 128, 0, stream>>>(hp, hp + (size_t)MROWS * CR, b_proj,
                                       ln1_g, ln1_b, hbuf, yb);
    // 4. qk (q scaled) + V^T = y @ wqkv^T
    gemm_mfma<CR, 12, 1><<<dim3(1152 / 128, MROWS / 128, 1), 256, 0, stream>>>(
        yb, wqkv, qkb, vtb);
    // 5. out = hsum + attention
    attn_mfma<<<dim3(NN / 128, BB * HEADS), 256, 0, stream>>>(qkb, vtb, hbuf, out);
}